// Round 7
// baseline (89.015 us; speedup 1.0000x reference)
//
#include <hip/hip_runtime.h>

// RBF kernel layer: K[b,n,m] = exp(-max(|a|^2+|b|^2-2ab,0)/(2*sigma^2))
// A: (8,2048,128) f32 -> flat (16384,128); B: (4096,128) f32; out (16384,4096) f32.
// Round 7: ZERO-LDS streaming kernel. Fragment loads go straight from L2/L3
// (lane layout gives 100% 64B-line utilization: 4 kb-lanes share each row's
// line). No barriers anywhere -> waves desync and self-smooth the write
// stream. 4 blocks/CU. Single-pass bf16 (absmax 2.6e-26 vs thr 1.1e-25),
// operand-swapped MFMA -> lane owns 4 consecutive out cols -> float4 stores.

typedef __attribute__((ext_vector_type(8))) short bf16x8;
typedef __attribute__((ext_vector_type(4))) float f32x4;

#define NROW_A 16384
#define NROW_B 4096
#define D      128

// ws layout (bytes)
#define OFF_AHI 0u
#define OFF_BHI (OFF_AHI + NROW_A * D * 2u)          // 4,194,304
#define OFF_NA  (OFF_BHI + NROW_B * D * 2u)          // 5,242,880
#define OFF_NB  (OFF_NA + NROW_A * 4u)               // 5,308,416
#define WS_NEED (OFF_NB + NROW_B * 4u)               // 5,324,800

__device__ __forceinline__ short f2bf_hi(float x) {
    union { float f; unsigned u; } v; v.f = x;
    unsigned r = (v.u + 0x7fffu + ((v.u >> 16) & 1u)) >> 16;  // RN-even
    return (short)r;
}
__device__ __forceinline__ float bf2f(short h) {
    union { unsigned u; float f; } v; v.u = ((unsigned)(unsigned short)h) << 16;
    return v.f;
}

// ---------------- precompute: f32 -> bf16 + row norms ----------------
__global__ __launch_bounds__(256)
void rbf_precompute(const float* __restrict__ A, const float* __restrict__ Bm,
                    short* __restrict__ Ahi, short* __restrict__ Bhi,
                    float* __restrict__ nA, float* __restrict__ nB) {
    const int g   = blockIdx.x * 256 + threadIdx.x;
    const int row = g >> 4;
    const int c   = g & 15;

    const float* src; short* dhi; float* nrm; int r;
    if (row < NROW_A) {
        r = row; src = A + (size_t)r * D;
        dhi = Ahi + (size_t)r * D; nrm = nA + r;
    } else {
        r = row - NROW_A; src = Bm + (size_t)r * D;
        dhi = Bhi + (size_t)r * D; nrm = nB + r;
    }

    float4 v0 = *(const float4*)(src + c * 8);
    float4 v1 = *(const float4*)(src + c * 8 + 4);
    float f[8] = {v0.x, v0.y, v0.z, v0.w, v1.x, v1.y, v1.z, v1.w};

    bf16x8 hi;
    float ss = 0.0f;
#pragma unroll
    for (int e = 0; e < 8; ++e) {
        hi[e] = f2bf_hi(f[e]);
        ss += f[e] * f[e];
    }
    *(bf16x8*)(dhi + c * 8) = hi;

#pragma unroll
    for (int m = 1; m <= 8; m <<= 1) ss += __shfl_xor(ss, m);
    if (c == 0) *nrm = ss;
}

// ---------------- main: zero-LDS streaming MFMA + exp epilogue ----------------
// 1024 blocks x 256 thr (4 waves). Block tile 64x128; each block sweeps 8
// brow tiles (512 rows). XCD-chunked bcol ownership keeps B panels (128KB/XCD)
// L2-resident; A (4MB bf16) is L3-resident.
__global__ __launch_bounds__(256, 4)   // 4 waves/EU -> 4 blocks/CU
void rbf_mfma_stream(const short* __restrict__ Ahi, const short* __restrict__ Bhi,
                     const float* __restrict__ nAg, const float* __restrict__ nBg,
                     const float* __restrict__ sigp, float* __restrict__ out) {
    const int tid = threadIdx.x;
    const int bid = blockIdx.x;
    const int xcd = bid & 7;
    const int bcol = ((xcd << 2) + ((bid >> 3) & 3)) << 7;   // 32 bcol panels
    const int bg   = bid >> 5;                               // 0..31

    const int lane = tid & 63;
    const int w    = tid >> 6;                 // 0..3
    const int wr   = (w >> 1) << 5;            // 0/32
    const int wc   = (w & 1) << 6;             // 0/64
    const int lr   = lane & 15;
    const int kb   = lane >> 4;                // 0..3

    float sg = fmaxf(sigp[0], 0.001f);
    const float cc = -0.5f / (sg * sg);

    // B norms are fixed per thread for the whole block: 4 x f32x4 in registers
    f32x4 nb[4];
#pragma unroll
    for (int j = 0; j < 4; ++j)
        nb[j] = *(const f32x4*)&nBg[bcol + wc + (j << 4) + (kb << 2)];

    for (int t = 0; t < 8; ++t) {
        const int browt = ((bg << 3) + t) << 6;    // 64-row tile

        f32x4 acc[2][4] = {};
#pragma unroll
        for (int ks = 0; ks < 4; ++ks) {
            const int koff = ((ks << 2) + kb) << 3;    // 8-elem chunk in K
            bf16x8 af[2], bf[4];
#pragma unroll
            for (int i = 0; i < 2; ++i)
                af[i] = *(const bf16x8*)&Ahi[(size_t)(browt + wr + (i << 4) + lr) * D + koff];
#pragma unroll
            for (int j = 0; j < 4; ++j)
                bf[j] = *(const bf16x8*)&Bhi[(size_t)(bcol + wc + (j << 4) + lr) * D + koff];
#pragma unroll
            for (int i = 0; i < 2; ++i)
#pragma unroll
                for (int j = 0; j < 4; ++j)
                    // swapped operands: D "row" dim = out COLS -> vector stores
                    acc[i][j] = __builtin_amdgcn_mfma_f32_16x16x32_bf16(bf[j], af[i], acc[i][j], 0, 0, 0);
        }

        // epilogue: dist2 -> exp; lane owns 4 consecutive out cols
#pragma unroll
        for (int i = 0; i < 2; ++i) {
            const int orow = browt + wr + (i << 4) + lr;
            const float na = nAg[orow];
#pragma unroll
            for (int j = 0; j < 4; ++j) {
                f32x4 v;
#pragma unroll
                for (int r = 0; r < 4; ++r) {
                    float d2 = fmaxf(na + nb[j][r] - 2.0f * acc[i][j][r], 0.0f);
                    v[r] = __expf(d2 * cc);
                }
                *(f32x4*)(out + (size_t)orow * 4096 + bcol + wc + (j << 4) + (kb << 2)) = v;
            }
        }
    }
}

// ---------------- fallback (self-contained, no ws; 3-pass split) ----------------
#define PK 136
__global__ __launch_bounds__(256, 2)
void rbf_mfma_fallback(const float* __restrict__ A, const float* __restrict__ Bm,
                       const float* __restrict__ sigp, float* __restrict__ out) {
    __shared__ __align__(16) short sAhi[64 * PK];
    __shared__ __align__(16) short sAlo[64 * PK];
    __shared__ __align__(16) short sBhi[64 * PK];
    __shared__ __align__(16) short sBlo[64 * PK];
    __shared__ float nA[64];
    __shared__ float nB[64];

    const int tid  = threadIdx.x;
    const int brow = blockIdx.y << 6;
    const int bcol = blockIdx.x << 6;

    const int r0 = tid >> 5;
    const int kq = (tid & 31) << 2;
#pragma unroll
    for (int it = 0; it < 8; ++it) {
        const int row = r0 + (it << 3);
        const float4 va = *(const float4*)(A  + (size_t)(brow + row) * 128 + kq);
        const float4 vb = *(const float4*)(Bm + (size_t)(bcol + row) * 128 + kq);
        short4 ha, la, hb, lb;
        ha.x = f2bf_hi(va.x); la.x = f2bf_hi(va.x - bf2f(ha.x));
        ha.y = f2bf_hi(va.y); la.y = f2bf_hi(va.y - bf2f(ha.y));
        ha.z = f2bf_hi(va.z); la.z = f2bf_hi(va.z - bf2f(ha.z));
        ha.w = f2bf_hi(va.w); la.w = f2bf_hi(va.w - bf2f(ha.w));
        hb.x = f2bf_hi(vb.x); lb.x = f2bf_hi(vb.x - bf2f(hb.x));
        hb.y = f2bf_hi(vb.y); lb.y = f2bf_hi(vb.y - bf2f(hb.y));
        hb.z = f2bf_hi(vb.z); lb.z = f2bf_hi(vb.z - bf2f(hb.z));
        hb.w = f2bf_hi(vb.w); lb.w = f2bf_hi(vb.w - bf2f(hb.w));
        const int idx = row * PK + kq;
        *(short4*)(&sAhi[idx]) = ha;
        *(short4*)(&sAlo[idx]) = la;
        *(short4*)(&sBhi[idx]) = hb;
        *(short4*)(&sBlo[idx]) = lb;
        float sa = va.x * va.x + va.y * va.y + va.z * va.z + va.w * va.w;
        float sb = vb.x * vb.x + vb.y * vb.y + vb.z * vb.z + vb.w * vb.w;
#pragma unroll
        for (int m = 16; m >= 1; m >>= 1) { sa += __shfl_xor(sa, m); sb += __shfl_xor(sb, m); }
        if ((tid & 31) == 0) { nA[row] = sa; nB[row] = sb; }
    }
    __syncthreads();

    const int lane = tid & 63;
    const int w    = tid >> 6;
    const int wr   = (w >> 1) << 5;
    const int wc   = (w & 1) << 5;
    const int lr   = lane & 15;
    const int kb   = lane >> 4;
    f32x4 acc[2][2] = {};
#pragma unroll
    for (int ks = 0; ks < 4; ++ks) {
        const int kc = (ks << 5) + (kb << 3);
        bf16x8 ahi[2], alo[2], bhi[2], blo[2];
#pragma unroll
        for (int i = 0; i < 2; ++i) {
            const int ar = (wr + (i << 4) + lr) * PK + kc;
            ahi[i] = *(const bf16x8*)(&sAhi[ar]);
            alo[i] = *(const bf16x8*)(&sAlo[ar]);
            const int br = (wc + (i << 4) + lr) * PK + kc;
            bhi[i] = *(const bf16x8*)(&sBhi[br]);
            blo[i] = *(const bf16x8*)(&sBlo[br]);
        }
#pragma unroll
        for (int i = 0; i < 2; ++i)
#pragma unroll
            for (int j = 0; j < 2; ++j) {
                acc[i][j] = __builtin_amdgcn_mfma_f32_16x16x32_bf16(ahi[i], bhi[j], acc[i][j], 0, 0, 0);
                acc[i][j] = __builtin_amdgcn_mfma_f32_16x16x32_bf16(ahi[i], blo[j], acc[i][j], 0, 0, 0);
                acc[i][j] = __builtin_amdgcn_mfma_f32_16x16x32_bf16(alo[i], bhi[j], acc[i][j], 0, 0, 0);
            }
    }
    float sg = fmaxf(sigp[0], 0.001f);
    const float c = -0.5f / (sg * sg);
#pragma unroll
    for (int i = 0; i < 2; ++i)
#pragma unroll
        for (int j = 0; j < 2; ++j)
#pragma unroll
            for (int r = 0; r < 4; ++r) {
                const int lrow = wr + (i << 4) + (kb << 2) + r;
                const int lcol = wc + (j << 4) + lr;
                float d2 = nA[lrow] + nB[lcol] - 2.0f * acc[i][j][r];
                d2 = fmaxf(d2, 0.0f);
                out[(size_t)(brow + lrow) * 4096 + (bcol + lcol)] = __expf(d2 * c);
            }
}

extern "C" void kernel_launch(void* const* d_in, const int* in_sizes, int n_in,
                              void* d_out, int out_size, void* d_ws, size_t ws_size,
                              hipStream_t stream) {
    const float* A    = (const float*)d_in[0];
    const float* Bm   = (const float*)d_in[1];
    const float* sigp = (const float*)d_in[2];
    float* out = (float*)d_out;

    if (ws_size >= WS_NEED) {
        char* ws = (char*)d_ws;
        short* Ahi = (short*)(ws + OFF_AHI);
        short* Bhi = (short*)(ws + OFF_BHI);
        float* nA  = (float*)(ws + OFF_NA);
        float* nB  = (float*)(ws + OFF_NB);

        dim3 pgrid((NROW_A + NROW_B) * 16 / 256, 1, 1);
        rbf_precompute<<<pgrid, 256, 0, stream>>>(A, Bm, Ahi, Bhi, nA, nB);

        // 1024 blocks: 32 bcol panels (XCD-chunked) x 32 brow groups
        rbf_mfma_stream<<<dim3(1024, 1, 1), dim3(256, 1, 1), 0, stream>>>(
            Ahi, Bhi, nA, nB, sigp, out);
    } else {
        dim3 grid(4096 / 64, 16384 / 64, 1);
        rbf_mfma_fallback<<<grid, dim3(256, 1, 1), 0, stream>>>(A, Bm, sigp, out);
    }
}

// Round 8
// 62.656 us; speedup vs baseline: 1.4207x; 1.4207x over previous
//
#include <hip/hip_runtime.h>

// RBF kernel layer: K[b,n,m] = exp(-max(|a|^2+|b|^2-2ab,0)/(2*sigma^2))
// A: (8,2048,128) f32 -> flat (16384,128); B: (4096,128) f32; out (16384,4096) f32.
// Round 8: round-6 structure (best, 60.1us) + T4 counted-wait barriers.
// __syncthreads drains vmcnt(0) = waits for all output STORES every tile; raw
// s_barrier + lgkmcnt(0) lets stores fly across barriers (prefetch loads are
// older than stores; vmcnt retires in order, compiler emits counted vmcnt for
// the ds_write deps). Norms moved out of LDS (regs), so LDS = sA+sB only.
// Single-pass bf16 (absmax 2.6e-26 vs thr 1.1e-25), persistent blocks,
// B staged once, operand-swapped MFMA -> float4 stores, chunk-XOR swizzle.

typedef __attribute__((ext_vector_type(8))) short bf16x8;
typedef __attribute__((ext_vector_type(4))) float f32x4;

#define NROW_A 16384
#define NROW_B 4096
#define D      128

// ws layout (bytes)
#define OFF_AHI 0u
#define OFF_BHI (OFF_AHI + NROW_A * D * 2u)          // 4,194,304
#define OFF_NA  (OFF_BHI + NROW_B * D * 2u)          // 5,242,880
#define OFF_NB  (OFF_NA + NROW_A * 4u)               // 5,308,416
#define WS_NEED (OFF_NB + NROW_B * 4u)               // 5,324,800

// raw barrier: ds-ops ordered, global stores NOT drained (unlike __syncthreads)
#define BAR_LDS() do { asm volatile("s_waitcnt lgkmcnt(0)" ::: "memory"); \
                       __builtin_amdgcn_s_barrier(); } while (0)

__device__ __forceinline__ short f2bf_hi(float x) {
    union { float f; unsigned u; } v; v.f = x;
    unsigned r = (v.u + 0x7fffu + ((v.u >> 16) & 1u)) >> 16;  // RN-even
    return (short)r;
}
__device__ __forceinline__ float bf2f(short h) {
    union { unsigned u; float f; } v; v.u = ((unsigned)(unsigned short)h) << 16;
    return v.f;
}

// ---------------- precompute: f32 -> bf16 + row norms ----------------
__global__ __launch_bounds__(256)
void rbf_precompute(const float* __restrict__ A, const float* __restrict__ Bm,
                    short* __restrict__ Ahi, short* __restrict__ Bhi,
                    float* __restrict__ nA, float* __restrict__ nB) {
    const int g   = blockIdx.x * 256 + threadIdx.x;
    const int row = g >> 4;
    const int c   = g & 15;

    const float* src; short* dhi; float* nrm; int r;
    if (row < NROW_A) {
        r = row; src = A + (size_t)r * D;
        dhi = Ahi + (size_t)r * D; nrm = nA + r;
    } else {
        r = row - NROW_A; src = Bm + (size_t)r * D;
        dhi = Bhi + (size_t)r * D; nrm = nB + r;
    }

    float4 v0 = *(const float4*)(src + c * 8);
    float4 v1 = *(const float4*)(src + c * 8 + 4);
    float f[8] = {v0.x, v0.y, v0.z, v0.w, v1.x, v1.y, v1.z, v1.w};

    bf16x8 hi;
    float ss = 0.0f;
#pragma unroll
    for (int e = 0; e < 8; ++e) {
        hi[e] = f2bf_hi(f[e]);
        ss += f[e] * f[e];
    }
    *(bf16x8*)(dhi + c * 8) = hi;

#pragma unroll
    for (int m = 1; m <= 8; m <<= 1) ss += __shfl_xor(ss, m);
    if (c == 0) *nrm = ss;
}

// ---------------- main: persistent 128x128 tiles, B resident ----------------
__global__ __launch_bounds__(512, 4)   // 4 waves/EU = 2 blocks/CU
void rbf_mfma_persist(const short* __restrict__ Ahi, const short* __restrict__ Bhi,
                      const float* __restrict__ nAg, const float* __restrict__ nBg,
                      const float* __restrict__ sigp, float* __restrict__ out) {
    __shared__ __align__(16) short sA[128 * 128];   // [row*128 + swz-chunk]
    __shared__ __align__(16) short sB[128 * 128];

    const int tid = threadIdx.x;
    const int bid = blockIdx.x;
    // XCD-chunked: xcd = bid&7 owns 4 bcol tiles; 16 brow-groups of 8 tiles.
    const int xcd = bid & 7;
    const int idx = bid >> 3;                 // 0..63
    const int bcol = ((xcd << 2) + (idx & 3)) << 7;
    const int bg   = idx >> 2;                // 0..15

    const int srow = tid >> 2;                // 0..127
    const int sc4  = tid & 3;

    const int lane = tid & 63;
    const int w    = tid >> 6;            // 0..7
    const int wr   = (w >> 1) << 5;       // 0/32/64/96
    const int wc   = (w & 1) << 6;        // 0/64
    const int lr   = lane & 15;
    const int kb   = lane >> 4;           // 0..3

    // ---- prologue: stage B panel; stage A(0); norms -> registers ----
#pragma unroll
    for (int it = 0; it < 4; ++it) {
        const int c  = sc4 + (it << 2);
        const int cs = c ^ (srow & 15);
        *(bf16x8*)&sB[srow * 128 + cs * 8] =
            *(const bf16x8*)&Bhi[(size_t)(bcol + srow) * D + c * 8];
    }
    {
        const int brow0 = (bg << 3) << 7;
#pragma unroll
        for (int it = 0; it < 4; ++it) {
            const int c  = sc4 + (it << 2);
            const int cs = c ^ (srow & 15);
            *(bf16x8*)&sA[srow * 128 + cs * 8] =
                *(const bf16x8*)&Ahi[(size_t)(brow0 + srow) * D + c * 8];
        }
    }

    // B norms: per-thread constant for whole block (4 x f32x4 in regs)
    f32x4 nb[4];
#pragma unroll
    for (int j = 0; j < 4; ++j)
        nb[j] = *(const f32x4*)&nBg[bcol + wc + (j << 4) + (kb << 2)];

    float sg = fmaxf(sigp[0], 0.001f);
    const float cc = -0.5f / (sg * sg);

    __syncthreads();   // once, prologue

    bf16x8 rh[4];

    for (int t = 0; t < 8; ++t) {
        const int browt = ((bg << 3) + t) << 7;

        // ---- prefetch: A(t+1) tile -> regs; A norms for THIS tile -> regs ----
        // (loads issued before this iter's stores: vmcnt in-order retire means
        //  the compiler's counted wait before ds_write won't drain the stores)
        const float na0 = nAg[browt + wr + lr];
        const float na1 = nAg[browt + wr + 16 + lr];
        if (t < 7) {
            const int brn = browt + 128;
#pragma unroll
            for (int it = 0; it < 4; ++it) {
                const int c = sc4 + (it << 2);
                rh[it] = *(const bf16x8*)&Ahi[(size_t)(brn + srow) * D + c * 8];
            }
        }

        // ---- compute: single-pass MFMA, operand-swapped ----
        f32x4 acc[2][4] = {};
#pragma unroll
        for (int ks = 0; ks < 4; ++ks) {
            const int off = (((ks << 2) + kb) ^ lr) << 3;
            bf16x8 af[2], bf[4];
#pragma unroll
            for (int i = 0; i < 2; ++i)
                af[i] = *(const bf16x8*)&sA[(wr + (i << 4) + lr) * 128 + off];
#pragma unroll
            for (int j = 0; j < 4; ++j)
                bf[j] = *(const bf16x8*)&sB[(wc + (j << 4) + lr) * 128 + off];
#pragma unroll
            for (int i = 0; i < 2; ++i)
#pragma unroll
                for (int j = 0; j < 4; ++j)
                    // swapped: first operand = B fragment -> D "row" dim = out COLS
                    acc[i][j] = __builtin_amdgcn_mfma_f32_16x16x32_bf16(bf[j], af[i], acc[i][j], 0, 0, 0);
        }

        // ---- epilogue: lane owns 4 consecutive out cols -> float4 store ----
#pragma unroll
        for (int i = 0; i < 2; ++i) {
            const int orow = browt + wr + (i << 4) + lr;
            const float na = i ? na1 : na0;
#pragma unroll
            for (int j = 0; j < 4; ++j) {
                const int ocol = wc + (j << 4) + (kb << 2);   // 4 consecutive cols
                f32x4 v;
#pragma unroll
                for (int r = 0; r < 4; ++r) {
                    float d2 = fmaxf(na + nb[j][r] - 2.0f * acc[i][j][r], 0.0f);
                    v[r] = __expf(d2 * cc);
                }
                *(f32x4*)(out + (size_t)orow * 4096 + bcol + ocol) = v;
            }
        }

        if (t < 7) {
            BAR_LDS();     // all waves done ds_reading sA(t); stores NOT drained
#pragma unroll
            for (int it = 0; it < 4; ++it) {
                const int c  = sc4 + (it << 2);
                const int cs = c ^ (srow & 15);
                *(bf16x8*)&sA[srow * 128 + cs * 8] = rh[it];
            }
            BAR_LDS();     // sA(t+1) visible to all waves
        }
    }
}

// ---------------- fallback (self-contained, no ws; 3-pass split) ----------------
#define PK 136
__global__ __launch_bounds__(256, 2)
void rbf_mfma_fallback(const float* __restrict__ A, const float* __restrict__ Bm,
                       const float* __restrict__ sigp, float* __restrict__ out) {
    __shared__ __align__(16) short sAhi[64 * PK];
    __shared__ __align__(16) short sAlo[64 * PK];
    __shared__ __align__(16) short sBhi[64 * PK];
    __shared__ __align__(16) short sBlo[64 * PK];
    __shared__ float nA[64];
    __shared__ float nB[64];

    const int tid  = threadIdx.x;
    const int brow = blockIdx.y << 6;
    const int bcol = blockIdx.x << 6;

    const int r0 = tid >> 5;
    const int kq = (tid & 31) << 2;
#pragma unroll
    for (int it = 0; it < 8; ++it) {
        const int row = r0 + (it << 3);
        const float4 va = *(const float4*)(A  + (size_t)(brow + row) * 128 + kq);
        const float4 vb = *(const float4*)(Bm + (size_t)(bcol + row) * 128 + kq);
        short4 ha, la, hb, lb;
        ha.x = f2bf_hi(va.x); la.x = f2bf_hi(va.x - bf2f(ha.x));
        ha.y = f2bf_hi(va.y); la.y = f2bf_hi(va.y - bf2f(ha.y));
        ha.z = f2bf_hi(va.z); la.z = f2bf_hi(va.z - bf2f(ha.z));
        ha.w = f2bf_hi(va.w); la.w = f2bf_hi(va.w - bf2f(ha.w));
        hb.x = f2bf_hi(vb.x); lb.x = f2bf_hi(vb.x - bf2f(hb.x));
        hb.y = f2bf_hi(vb.y); lb.y = f2bf_hi(vb.y - bf2f(hb.y));
        hb.z = f2bf_hi(vb.z); lb.z = f2bf_hi(vb.z - bf2f(hb.z));
        hb.w = f2bf_hi(vb.w); lb.w = f2bf_hi(vb.w - bf2f(hb.w));
        const int idx = row * PK + kq;
        *(short4*)(&sAhi[idx]) = ha;
        *(short4*)(&sAlo[idx]) = la;
        *(short4*)(&sBhi[idx]) = hb;
        *(short4*)(&sBlo[idx]) = lb;
        float sa = va.x * va.x + va.y * va.y + va.z * va.z + va.w * va.w;
        float sb = vb.x * vb.x + vb.y * vb.y + vb.z * vb.z + vb.w * vb.w;
#pragma unroll
        for (int m = 16; m >= 1; m >>= 1) { sa += __shfl_xor(sa, m); sb += __shfl_xor(sb, m); }
        if ((tid & 31) == 0) { nA[row] = sa; nB[row] = sb; }
    }
    __syncthreads();

    const int lane = tid & 63;
    const int w    = tid >> 6;
    const int wr   = (w >> 1) << 5;
    const int wc   = (w & 1) << 5;
    const int lr   = lane & 15;
    const int kb   = lane >> 4;
    f32x4 acc[2][2] = {};
#pragma unroll
    for (int ks = 0; ks < 4; ++ks) {
        const int kc = (ks << 5) + (kb << 3);
        bf16x8 ahi[2], alo[2], bhi[2], blo[2];
#pragma unroll
        for (int i = 0; i < 2; ++i) {
            const int ar = (wr + (i << 4) + lr) * PK + kc;
            ahi[i] = *(const bf16x8*)(&sAhi[ar]);
            alo[i] = *(const bf16x8*)(&sAlo[ar]);
            const int br = (wc + (i << 4) + lr) * PK + kc;
            bhi[i] = *(const bf16x8*)(&sBhi[br]);
            blo[i] = *(const bf16x8*)(&sBlo[br]);
        }
#pragma unroll
        for (int i = 0; i < 2; ++i)
#pragma unroll
            for (int j = 0; j < 2; ++j) {
                acc[i][j] = __builtin_amdgcn_mfma_f32_16x16x32_bf16(ahi[i], bhi[j], acc[i][j], 0, 0, 0);
                acc[i][j] = __builtin_amdgcn_mfma_f32_16x16x32_bf16(ahi[i], blo[j], acc[i][j], 0, 0, 0);
                acc[i][j] = __builtin_amdgcn_mfma_f32_16x16x32_bf16(alo[i], bhi[j], acc[i][j], 0, 0, 0);
            }
    }
    float sg = fmaxf(sigp[0], 0.001f);
    const float c = -0.5f / (sg * sg);
#pragma unroll
    for (int i = 0; i < 2; ++i)
#pragma unroll
        for (int j = 0; j < 2; ++j)
#pragma unroll
            for (int r = 0; r < 4; ++r) {
                const int lrow = wr + (i << 4) + (kb << 2) + r;
                const int lcol = wc + (j << 4) + lr;
                float d2 = nA[lrow] + nB[lcol] - 2.0f * acc[i][j][r];
                d2 = fmaxf(d2, 0.0f);
                out[(size_t)(brow + lrow) * 4096 + (bcol + lcol)] = __expf(d2 * c);
            }
}

extern "C" void kernel_launch(void* const* d_in, const int* in_sizes, int n_in,
                              void* d_out, int out_size, void* d_ws, size_t ws_size,
                              hipStream_t stream) {
    const float* A    = (const float*)d_in[0];
    const float* Bm   = (const float*)d_in[1];
    const float* sigp = (const float*)d_in[2];
    float* out = (float*)d_out;

    if (ws_size >= WS_NEED) {
        char* ws = (char*)d_ws;
        short* Ahi = (short*)(ws + OFF_AHI);
        short* Bhi = (short*)(ws + OFF_BHI);
        float* nA  = (float*)(ws + OFF_NA);
        float* nB  = (float*)(ws + OFF_NB);

        dim3 pgrid((NROW_A + NROW_B) * 16 / 256, 1, 1);
        rbf_precompute<<<pgrid, 256, 0, stream>>>(A, Bm, Ahi, Bhi, nA, nB);

        // 512 persistent-ish blocks: 32 bcol tiles x 16 brow-groups (8 tiles each)
        rbf_mfma_persist<<<dim3(512, 1, 1), dim3(512, 1, 1), 0, stream>>>(
            Ahi, Bhi, nA, nB, sigp, out);
    } else {
        dim3 grid(4096 / 64, 16384 / 64, 1);
        rbf_mfma_fallback<<<grid, dim3(256, 1, 1), 0, stream>>>(A, Bm, sigp, out);
    }
}

// Round 9
// 60.151 us; speedup vs baseline: 1.4799x; 1.0416x over previous
//
#include <hip/hip_runtime.h>

// RBF kernel layer: K[b,n,m] = exp(-max(|a|^2+|b|^2-2ab,0)/(2*sigma^2))
// A: (8,2048,128) f32 -> flat (16384,128); B: (4096,128) f32; out (16384,4096) f32.
// Round 9: round-8 + ROTATED na prefetch. vmcnt retires in issue order, so any
// load issued AFTER period-t stores forces a full store-burst drain when
// consumed (the hidden per-period stall). Fix: load na(t+1) BEFORE period-t
// stores are issued (with the rh prefetch); epilogue(t+1) then consumes only
// loads OLDER than the previous store burst -> no drain-wait, stores stream.
// Single-pass bf16 (absmax 2.6e-26 vs thr 1.1e-25), persistent blocks,
// B staged once, raw lgkmcnt barriers, operand-swapped MFMA, chunk-XOR swizzle.

typedef __attribute__((ext_vector_type(8))) short bf16x8;
typedef __attribute__((ext_vector_type(4))) float f32x4;

#define NROW_A 16384
#define NROW_B 4096
#define D      128

// ws layout (bytes)
#define OFF_AHI 0u
#define OFF_BHI (OFF_AHI + NROW_A * D * 2u)          // 4,194,304
#define OFF_NA  (OFF_BHI + NROW_B * D * 2u)          // 5,242,880
#define OFF_NB  (OFF_NA + NROW_A * 4u)               // 5,308,416
#define WS_NEED (OFF_NB + NROW_B * 4u)               // 5,324,800

// raw barrier: ds-ops ordered, global stores NOT drained (unlike __syncthreads)
#define BAR_LDS() do { asm volatile("s_waitcnt lgkmcnt(0)" ::: "memory"); \
                       __builtin_amdgcn_s_barrier(); } while (0)

__device__ __forceinline__ short f2bf_hi(float x) {
    union { float f; unsigned u; } v; v.f = x;
    unsigned r = (v.u + 0x7fffu + ((v.u >> 16) & 1u)) >> 16;  // RN-even
    return (short)r;
}
__device__ __forceinline__ float bf2f(short h) {
    union { unsigned u; float f; } v; v.u = ((unsigned)(unsigned short)h) << 16;
    return v.f;
}

// ---------------- precompute: f32 -> bf16 + row norms ----------------
__global__ __launch_bounds__(256)
void rbf_precompute(const float* __restrict__ A, const float* __restrict__ Bm,
                    short* __restrict__ Ahi, short* __restrict__ Bhi,
                    float* __restrict__ nA, float* __restrict__ nB) {
    const int g   = blockIdx.x * 256 + threadIdx.x;
    const int row = g >> 4;
    const int c   = g & 15;

    const float* src; short* dhi; float* nrm; int r;
    if (row < NROW_A) {
        r = row; src = A + (size_t)r * D;
        dhi = Ahi + (size_t)r * D; nrm = nA + r;
    } else {
        r = row - NROW_A; src = Bm + (size_t)r * D;
        dhi = Bhi + (size_t)r * D; nrm = nB + r;
    }

    float4 v0 = *(const float4*)(src + c * 8);
    float4 v1 = *(const float4*)(src + c * 8 + 4);
    float f[8] = {v0.x, v0.y, v0.z, v0.w, v1.x, v1.y, v1.z, v1.w};

    bf16x8 hi;
    float ss = 0.0f;
#pragma unroll
    for (int e = 0; e < 8; ++e) {
        hi[e] = f2bf_hi(f[e]);
        ss += f[e] * f[e];
    }
    *(bf16x8*)(dhi + c * 8) = hi;

#pragma unroll
    for (int m = 1; m <= 8; m <<= 1) ss += __shfl_xor(ss, m);
    if (c == 0) *nrm = ss;
}

// ---------------- main: persistent 128x128 tiles, B resident ----------------
__global__ __launch_bounds__(512, 4)   // 4 waves/EU = 2 blocks/CU
void rbf_mfma_persist(const short* __restrict__ Ahi, const short* __restrict__ Bhi,
                      const float* __restrict__ nAg, const float* __restrict__ nBg,
                      const float* __restrict__ sigp, float* __restrict__ out) {
    __shared__ __align__(16) short sA[128 * 128];   // [row*128 + swz-chunk]
    __shared__ __align__(16) short sB[128 * 128];

    const int tid = threadIdx.x;
    const int bid = blockIdx.x;
    // XCD-chunked: xcd = bid&7 owns 4 bcol tiles; 16 brow-groups of 8 tiles.
    const int xcd = bid & 7;
    const int idx = bid >> 3;                 // 0..63
    const int bcol = ((xcd << 2) + (idx & 3)) << 7;
    const int bg   = idx >> 2;                // 0..15

    const int srow = tid >> 2;                // 0..127
    const int sc4  = tid & 3;

    const int lane = tid & 63;
    const int w    = tid >> 6;            // 0..7
    const int wr   = (w >> 1) << 5;       // 0/32/64/96
    const int wc   = (w & 1) << 6;        // 0/64
    const int lr   = lane & 15;
    const int kb   = lane >> 4;           // 0..3

    // ---- prologue: stage B panel; stage A(0); norms -> registers ----
#pragma unroll
    for (int it = 0; it < 4; ++it) {
        const int c  = sc4 + (it << 2);
        const int cs = c ^ (srow & 15);
        *(bf16x8*)&sB[srow * 128 + cs * 8] =
            *(const bf16x8*)&Bhi[(size_t)(bcol + srow) * D + c * 8];
    }
    const int brow0 = (bg << 3) << 7;
#pragma unroll
    for (int it = 0; it < 4; ++it) {
        const int c  = sc4 + (it << 2);
        const int cs = c ^ (srow & 15);
        *(bf16x8*)&sA[srow * 128 + cs * 8] =
            *(const bf16x8*)&Ahi[(size_t)(brow0 + srow) * D + c * 8];
    }

    // B norms: per-thread constant for whole block (4 x f32x4 in regs)
    f32x4 nb[4];
#pragma unroll
    for (int j = 0; j < 4; ++j)
        nb[j] = *(const f32x4*)&nBg[bcol + wc + (j << 4) + (kb << 2)];

    // A norms for tile 0 (issued in prologue, before ANY stores)
    float nac0 = nAg[brow0 + wr + lr];
    float nac1 = nAg[brow0 + wr + 16 + lr];

    float sg = fmaxf(sigp[0], 0.001f);
    const float cc = -0.5f / (sg * sg);

    __syncthreads();   // once, prologue

    bf16x8 rh[4];
    float nan0 = 0.0f, nan1 = 0.0f;

    for (int t = 0; t < 8; ++t) {
        const int browt = ((bg << 3) + t) << 7;

        // ---- prefetch NEXT period's A-tile + A-norms (issued BEFORE this
        //      period's stores -> consuming them never drains a store burst) ----
        if (t < 7) {
            const int brn = browt + 128;
            nan0 = nAg[brn + wr + lr];
            nan1 = nAg[brn + wr + 16 + lr];
#pragma unroll
            for (int it = 0; it < 4; ++it) {
                const int c = sc4 + (it << 2);
                rh[it] = *(const bf16x8*)&Ahi[(size_t)(brn + srow) * D + c * 8];
            }
        }

        // ---- compute: single-pass MFMA, operand-swapped ----
        f32x4 acc[2][4] = {};
#pragma unroll
        for (int ks = 0; ks < 4; ++ks) {
            const int off = (((ks << 2) + kb) ^ lr) << 3;
            bf16x8 af[2], bf[4];
#pragma unroll
            for (int i = 0; i < 2; ++i)
                af[i] = *(const bf16x8*)&sA[(wr + (i << 4) + lr) * 128 + off];
#pragma unroll
            for (int j = 0; j < 4; ++j)
                bf[j] = *(const bf16x8*)&sB[(wc + (j << 4) + lr) * 128 + off];
#pragma unroll
            for (int i = 0; i < 2; ++i)
#pragma unroll
                for (int j = 0; j < 4; ++j)
                    // swapped: first operand = B fragment -> D "row" dim = out COLS
                    acc[i][j] = __builtin_amdgcn_mfma_f32_16x16x32_bf16(bf[j], af[i], acc[i][j], 0, 0, 0);
        }

        // ---- epilogue: uses only pre-store-issued loads; float4 stores ----
#pragma unroll
        for (int i = 0; i < 2; ++i) {
            const int orow = browt + wr + (i << 4) + lr;
            const float na = i ? nac1 : nac0;
#pragma unroll
            for (int j = 0; j < 4; ++j) {
                const int ocol = wc + (j << 4) + (kb << 2);   // 4 consecutive cols
                f32x4 v;
#pragma unroll
                for (int r = 0; r < 4; ++r) {
                    float d2 = fmaxf(na + nb[j][r] - 2.0f * acc[i][j][r], 0.0f);
                    v[r] = __expf(d2 * cc);
                }
                *(f32x4*)(out + (size_t)orow * 4096 + bcol + ocol) = v;
            }
        }

        if (t < 7) {
            BAR_LDS();     // all waves done ds_reading sA(t); stores NOT drained
#pragma unroll
            for (int it = 0; it < 4; ++it) {
                const int c  = sc4 + (it << 2);
                const int cs = c ^ (srow & 15);
                *(bf16x8*)&sA[srow * 128 + cs * 8] = rh[it];
            }
            BAR_LDS();     // sA(t+1) visible to all waves
            nac0 = nan0;   // rotate: next period's norms (already in flight/done)
            nac1 = nan1;
        }
    }
}

// ---------------- fallback (self-contained, no ws; 3-pass split) ----------------
#define PK 136
__global__ __launch_bounds__(256, 2)
void rbf_mfma_fallback(const float* __restrict__ A, const float* __restrict__ Bm,
                       const float* __restrict__ sigp, float* __restrict__ out) {
    __shared__ __align__(16) short sAhi[64 * PK];
    __shared__ __align__(16) short sAlo[64 * PK];
    __shared__ __align__(16) short sBhi[64 * PK];
    __shared__ __align__(16) short sBlo[64 * PK];
    __shared__ float nA[64];
    __shared__ float nB[64];

    const int tid  = threadIdx.x;
    const int brow = blockIdx.y << 6;
    const int bcol = blockIdx.x << 6;

    const int r0 = tid >> 5;
    const int kq = (tid & 31) << 2;
#pragma unroll
    for (int it = 0; it < 8; ++it) {
        const int row = r0 + (it << 3);
        const float4 va = *(const float4*)(A  + (size_t)(brow + row) * 128 + kq);
        const float4 vb = *(const float4*)(Bm + (size_t)(bcol + row) * 128 + kq);
        short4 ha, la, hb, lb;
        ha.x = f2bf_hi(va.x); la.x = f2bf_hi(va.x - bf2f(ha.x));
        ha.y = f2bf_hi(va.y); la.y = f2bf_hi(va.y - bf2f(ha.y));
        ha.z = f2bf_hi(va.z); la.z = f2bf_hi(va.z - bf2f(ha.z));
        ha.w = f2bf_hi(va.w); la.w = f2bf_hi(va.w - bf2f(ha.w));
        hb.x = f2bf_hi(vb.x); lb.x = f2bf_hi(vb.x - bf2f(hb.x));
        hb.y = f2bf_hi(vb.y); lb.y = f2bf_hi(vb.y - bf2f(hb.y));
        hb.z = f2bf_hi(vb.z); lb.z = f2bf_hi(vb.z - bf2f(hb.z));
        hb.w = f2bf_hi(vb.w); lb.w = f2bf_hi(vb.w - bf2f(hb.w));
        const int idx = row * PK + kq;
        *(short4*)(&sAhi[idx]) = ha;
        *(short4*)(&sAlo[idx]) = la;
        *(short4*)(&sBhi[idx]) = hb;
        *(short4*)(&sBlo[idx]) = lb;
        float sa = va.x * va.x + va.y * va.y + va.z * va.z + va.w * va.w;
        float sb = vb.x * vb.x + vb.y * vb.y + vb.z * vb.z + vb.w * vb.w;
#pragma unroll
        for (int m = 16; m >= 1; m >>= 1) { sa += __shfl_xor(sa, m); sb += __shfl_xor(sb, m); }
        if ((tid & 31) == 0) { nA[row] = sa; nB[row] = sb; }
    }
    __syncthreads();

    const int lane = tid & 63;
    const int w    = tid >> 6;
    const int wr   = (w >> 1) << 5;
    const int wc   = (w & 1) << 5;
    const int lr   = lane & 15;
    const int kb   = lane >> 4;
    f32x4 acc[2][2] = {};
#pragma unroll
    for (int ks = 0; ks < 4; ++ks) {
        const int kc = (ks << 5) + (kb << 3);
        bf16x8 ahi[2], alo[2], bhi[2], blo[2];
#pragma unroll
        for (int i = 0; i < 2; ++i) {
            const int ar = (wr + (i << 4) + lr) * PK + kc;
            ahi[i] = *(const bf16x8*)(&sAhi[ar]);
            alo[i] = *(const bf16x8*)(&sAlo[ar]);
            const int br = (wc + (i << 4) + lr) * PK + kc;
            bhi[i] = *(const bf16x8*)(&sBhi[br]);
            blo[i] = *(const bf16x8*)(&sBlo[br]);
        }
#pragma unroll
        for (int i = 0; i < 2; ++i)
#pragma unroll
            for (int j = 0; j < 2; ++j) {
                acc[i][j] = __builtin_amdgcn_mfma_f32_16x16x32_bf16(ahi[i], bhi[j], acc[i][j], 0, 0, 0);
                acc[i][j] = __builtin_amdgcn_mfma_f32_16x16x32_bf16(ahi[i], blo[j], acc[i][j], 0, 0, 0);
                acc[i][j] = __builtin_amdgcn_mfma_f32_16x16x32_bf16(alo[i], bhi[j], acc[i][j], 0, 0, 0);
            }
    }
    float sg = fmaxf(sigp[0], 0.001f);
    const float c = -0.5f / (sg * sg);
#pragma unroll
    for (int i = 0; i < 2; ++i)
#pragma unroll
        for (int j = 0; j < 2; ++j)
#pragma unroll
            for (int r = 0; r < 4; ++r) {
                const int lrow = wr + (i << 4) + (kb << 2) + r;
                const int lcol = wc + (j << 4) + lr;
                float d2 = nA[lrow] + nB[lcol] - 2.0f * acc[i][j][r];
                d2 = fmaxf(d2, 0.0f);
                out[(size_t)(brow + lrow) * 4096 + (bcol + lcol)] = __expf(d2 * c);
            }
}

extern "C" void kernel_launch(void* const* d_in, const int* in_sizes, int n_in,
                              void* d_out, int out_size, void* d_ws, size_t ws_size,
                              hipStream_t stream) {
    const float* A    = (const float*)d_in[0];
    const float* Bm   = (const float*)d_in[1];
    const float* sigp = (const float*)d_in[2];
    float* out = (float*)d_out;

    if (ws_size >= WS_NEED) {
        char* ws = (char*)d_ws;
        short* Ahi = (short*)(ws + OFF_AHI);
        short* Bhi = (short*)(ws + OFF_BHI);
        float* nA  = (float*)(ws + OFF_NA);
        float* nB  = (float*)(ws + OFF_NB);

        dim3 pgrid((NROW_A + NROW_B) * 16 / 256, 1, 1);
        rbf_precompute<<<pgrid, 256, 0, stream>>>(A, Bm, Ahi, Bhi, nA, nB);

        // 512 persistent-ish blocks: 32 bcol tiles x 16 brow-groups (8 tiles each)
        rbf_mfma_persist<<<dim3(512, 1, 1), dim3(512, 1, 1), 0, stream>>>(
            Ahi, Bhi, nA, nB, sigp, out);
    } else {
        dim3 grid(4096 / 64, 16384 / 64, 1);
        rbf_mfma_fallback<<<grid, dim3(256, 1, 1), 0, stream>>>(A, Bm, sigp, out);
    }
}